// Round 12
// baseline (184.502 us; speedup 1.0000x reference)
//
#include <hip/hip_runtime.h>
#include <hip/hip_bf16.h>
#include <math.h>

#define DICT 400000
#define D 128
#define NPAIR (DICT / 2)
#define G1 2048
#define KEYS_OFF 273
#define VALS_OFF (273 + DICT * D)
#define SHIFT 16.0f  // fixed softmax shift; cancels in num/den.

typedef float vfloat4 __attribute__((ext_vector_type(4)));

// ---------------- k_pre: preact = W_i2h@x + b_i2h + W_h2h@h + b_h2h (640 rows)
__global__ __launch_bounds__(256) void k_pre(const float* __restrict__ Wi,
                                             const float* __restrict__ bi,
                                             const float* __restrict__ Wh,
                                             const float* __restrict__ bh,
                                             const float* __restrict__ x,
                                             const float* __restrict__ h,
                                             float* __restrict__ pre) {
    const int lane = threadIdx.x & 63;
    const int row = blockIdx.x * 4 + (threadIdx.x >> 6);
    if (row >= 640) return;
    float2 xv = reinterpret_cast<const float2*>(x)[lane];
    float2 hv = reinterpret_cast<const float2*>(h)[lane];
    float2 wi = reinterpret_cast<const float2*>(Wi + row * D)[lane];
    float2 wh = reinterpret_cast<const float2*>(Wh + row * D)[lane];
    float dot = wi.x * xv.x + wi.y * xv.y + wh.x * hv.x + wh.y * hv.y;
#pragma unroll
    for (int off = 32; off; off >>= 1) dot += __shfl_xor(dot, off);
    if (lane == 0) pre[row] = dot + bi[row] + bh[row];
}

// Aligned-window store for pair p (single stream): dst floats
// [(2p+1)*128+15, +256) = 8 full 128B lines, one 1KB wave burst.
// Lane L gets src floats 2p*128+15+4L..: comp0 from srclane L+3 (.w),
// comps1-3 from srclane L+4 (.x/.y/.z); wrap lanes source the NEXT row's
// head (ek lanes 0..3). kv holds src floats 2p*128+4*lane..+4 per lane.
__device__ __forceinline__ void store_window1(float* __restrict__ dst,
                                              vfloat4 kv, vfloat4 ek,
                                              int lane, int idx3, int idx4,
                                              int p, bool last) {
    vfloat4 ks;
    float s;
    s = (lane < 3) ? ek.w : kv.w;  ks.x = __shfl(s, idx3);
    s = (lane < 4) ? ek.x : kv.x;  ks.y = __shfl(s, idx4);
    s = (lane < 4) ? ek.y : kv.y;  ks.z = __shfl(s, idx4);
    s = (lane < 4) ? ek.z : kv.z;  ks.w = __shfl(s, idx4);
    size_t base = (size_t)(2 * p + 1) * 128 + 15 + 4 * (size_t)lane;
    if (!last) {
        *reinterpret_cast<vfloat4*>(dst + base) = ks;
    } else {
        if (lane < 28) *reinterpret_cast<vfloat4*>(dst + base) = ks;
        else if (lane == 28) dst[base] = ks.x;
    }
}

// ---------------- k_dict: PHASE-SPLIT fused sweep, 32 waves/CU.
// launch_bounds(256, 8) caps VGPR at 64 -> all 8 blocks/CU co-resident
// (2048 blocks = exactly 8 x 256 CUs, no batch tail). Each phase = 1 read
// + 1 write stream per wave (the m13 copy mix). Strided mapping, aligned
// windows, cached loads.
__global__ __launch_bounds__(256, 8) void k_dict(const float* __restrict__ keys,
                                                 const float* __restrict__ vals,
                                                 const float* __restrict__ x,
                                                 float* __restrict__ keys_new,
                                                 float* __restrict__ vals_new,
                                                 float* __restrict__ partials) {
    const int tid = threadIdx.x;
    const int lane = tid & 63;
    const int half = lane >> 5;   // which row of the pair
    const int hl = lane & 31;     // lane within 32-lane half (4 floats each)
    const int wv = tid >> 6;      // wave in block
    const int idx3 = (lane + 3) & 63;
    const int idx4 = (lane + 4) & 63;
    const int wave = (blockIdx.x * blockDim.x + tid) >> 6;
    const int nw = (gridDim.x * blockDim.x) >> 6;
    const float4 xv = reinterpret_cast<const float4*>(x)[hl];

    // e storage: [wave][4*iter + 2*half + j]; <=13 iters/wave at nw=8192
    __shared__ float e_lds[4][104];

    float den = 0.f;

    // ---------------- PHASE 1: keys ----------------
    {
        int it = 0;
        for (int pp = 2 * wave; pp < NPAIR; pp += 2 * nw, ++it) {
            const int row0 = 2 * pp + half;
            const int row1 = row0 + 2;
            vfloat4 kv0 = reinterpret_cast<const vfloat4*>(keys + (size_t)row0 * D)[hl];
            vfloat4 kv1 = reinterpret_cast<const vfloat4*>(keys + (size_t)row1 * D)[hl];
            vfloat4 ek1 = (vfloat4)(0.f);
            if (lane < 4) {
                const int erow = min(2 * pp + 4, DICT - 1);  // clamp: junk unused
                ek1 = *reinterpret_cast<const vfloat4*>(keys + (size_t)erow * D + 4 * lane);
            }

            float dx = kv0.x - xv.x, dy = kv0.y - xv.y, dz = kv0.z - xv.z, dw = kv0.w - xv.w;
            float d20 = dx * dx + dy * dy + dz * dz + dw * dw;
            dx = kv1.x - xv.x; dy = kv1.y - xv.y; dz = kv1.z - xv.z; dw = kv1.w - xv.w;
            float d21 = dx * dx + dy * dy + dz * dz + dw * dw;
#pragma unroll
            for (int off = 16; off; off >>= 1) {
                d20 += __shfl_xor(d20, off);
                d21 += __shfl_xor(d21, off);
            }
            float e0 = __expf(SHIFT - sqrtf(d20 + 1e-6f));
            float e1 = __expf(SHIFT - sqrtf(d21 + 1e-6f));
            den += e0 + e1;
            if (hl == 0) {
                e_lds[wv][4 * it + 2 * half + 0] = e0;
                e_lds[wv][4 * it + 2 * half + 1] = e1;
            }

            if (pp == 0 && lane < 15) keys_new[128 + lane] = keys[lane];
            store_window1(keys_new, kv0, kv1, lane, idx3, idx4, pp, false);
            store_window1(keys_new, kv1, ek1, lane, idx3, idx4, pp + 1,
                          pp + 1 == NPAIR - 1);
        }
    }

    // ---------------- PHASE 2: vals ----------------
    vfloat4 acc = (vfloat4)(0.f);
    {
        int it = 0;
        for (int pp = 2 * wave; pp < NPAIR; pp += 2 * nw, ++it) {
            const int row0 = 2 * pp + half;
            const int row1 = row0 + 2;
            vfloat4 vv0 = reinterpret_cast<const vfloat4*>(vals + (size_t)row0 * D)[hl];
            vfloat4 vv1 = reinterpret_cast<const vfloat4*>(vals + (size_t)row1 * D)[hl];
            vfloat4 ev1 = (vfloat4)(0.f);
            if (lane < 4) {
                const int erow = min(2 * pp + 4, DICT - 1);
                ev1 = *reinterpret_cast<const vfloat4*>(vals + (size_t)erow * D + 4 * lane);
            }

            float e0 = e_lds[wv][4 * it + 2 * half + 0];
            float e1 = e_lds[wv][4 * it + 2 * half + 1];
            acc.x += e0 * vv0.x + e1 * vv1.x;
            acc.y += e0 * vv0.y + e1 * vv1.y;
            acc.z += e0 * vv0.z + e1 * vv1.z;
            acc.w += e0 * vv0.w + e1 * vv1.w;

            if (pp == 0 && lane < 15) vals_new[128 + lane] = vals[lane];
            store_window1(vals_new, vv0, vv1, lane, idx3, idx4, pp, false);
            store_window1(vals_new, vv1, ev1, lane, idx3, idx4, pp + 1,
                          pp + 1 == NPAIR - 1);
        }
    }

    // merge the two halves (even/odd rows; same component mapping)
    acc.x += __shfl_xor(acc.x, 32);
    acc.y += __shfl_xor(acc.y, 32);
    acc.z += __shfl_xor(acc.z, 32);
    acc.w += __shfl_xor(acc.w, 32);
    den += __shfl_xor(den, 32);

    __shared__ float lnum[4][128];
    __shared__ float lden[4];
    if (lane < 32) {
        lnum[wv][hl * 4 + 0] = acc.x;
        lnum[wv][hl * 4 + 1] = acc.y;
        lnum[wv][hl * 4 + 2] = acc.z;
        lnum[wv][hl * 4 + 3] = acc.w;
    }
    if (lane == 0) lden[wv] = den;
    __syncthreads();
    if (tid < 128) {
        float s = lnum[0][tid] + lnum[1][tid] + lnum[2][tid] + lnum[3][tid];
        partials[(size_t)tid * G1 + blockIdx.x] = s;   // [129][G1] layout
    } else if (tid == 128) {
        partials[(size_t)128 * G1 + blockIdx.x] = lden[0] + lden[1] + lden[2] + lden[3];
    }
}

// ---------------- k_red: reduce partials[129][G1] -> red[129] (coalesced)
__global__ __launch_bounds__(256) void k_red(const float* __restrict__ partials,
                                             float* __restrict__ red) {
    const int j = blockIdx.x;  // 0..128
    float s = 0.f;
    for (int b = threadIdx.x; b < G1; b += 256) s += partials[(size_t)j * G1 + b];
#pragma unroll
    for (int off = 32; off; off >>= 1) s += __shfl_xor(s, off);
    __shared__ float w4[4];
    if ((threadIdx.x & 63) == 0) w4[threadIdx.x >> 6] = s;
    __syncthreads();
    if (threadIdx.x == 0) red[j] = w4[0] + w4[1] + w4[2] + w4[3];
}

// ---------------- k_tail: m_t, LSTM cell, heads, row-0 writes. 1 block.
__global__ __launch_bounds__(256) void k_tail(const float* __restrict__ red,
                                              const float* __restrict__ pre,
                                              const float* __restrict__ x,
                                              const float* __restrict__ c,
                                              const float* __restrict__ Wa,
                                              const float* __restrict__ ba,
                                              const float* __restrict__ Wc,
                                              const float* __restrict__ bc,
                                              float* __restrict__ out) {
    __shared__ float sh_h[128];
    __shared__ float sh_logit[16];
    const int tid = threadIdx.x;
    if (tid < 128) {
        float den = red[128];
        float m = tanhf(red[tid] / den);
        float f  = 1.f / (1.f + __expf(-pre[tid]));
        float i_ = 1.f / (1.f + __expf(-pre[128 + tid]));
        float o  = 1.f / (1.f + __expf(-pre[256 + tid]));
        float r  = 1.f / (1.f + __expf(-pre[384 + tid]));
        float cn = tanhf(pre[512 + tid]);
        float ct = f * c[tid] + i_ * cn + r * m;
        float ht = o * tanhf(ct);
        sh_h[tid] = ht;
        out[17 + tid] = ht;            // h_t
        out[145 + tid] = ct;           // c_t
        out[KEYS_OFF + tid] = x[tid];  // keys_new row 0
        out[VALS_OFF + tid] = ct;      // vals_new row 0
    }
    __syncthreads();
    if (tid < 16) {
        float l = ba[tid];
        for (int j = 0; j < 128; ++j) l += Wa[tid * D + j] * sh_h[j];
        sh_logit[tid] = l;
    } else if (tid == 16) {
        float v = bc[0];
        for (int j = 0; j < 128; ++j) v += Wc[j] * sh_h[j];
        out[16] = v;
    }
    __syncthreads();
    if (tid == 0) {
        float mx = sh_logit[0];
        for (int k = 1; k < 16; ++k) mx = fmaxf(mx, sh_logit[k]);
        float e[16];
        float s = 0.f;
        for (int k = 0; k < 16; ++k) { e[k] = __expf(sh_logit[k] - mx); s += e[k]; }
        for (int k = 0; k < 16; ++k) out[k] = e[k] / s;
    }
}

extern "C" void kernel_launch(void* const* d_in, const int* in_sizes, int n_in,
                              void* d_out, int out_size, void* d_ws, size_t ws_size,
                              hipStream_t stream) {
    const float* x    = (const float*)d_in[0];
    const float* h    = (const float*)d_in[1];
    const float* c    = (const float*)d_in[2];
    const float* Wi   = (const float*)d_in[3];
    const float* bi   = (const float*)d_in[4];
    const float* Wh   = (const float*)d_in[5];
    const float* bh   = (const float*)d_in[6];
    const float* keys = (const float*)d_in[7];
    const float* vals = (const float*)d_in[8];
    const float* Wa   = (const float*)d_in[9];
    const float* ba   = (const float*)d_in[10];
    const float* Wc   = (const float*)d_in[11];
    const float* bc   = (const float*)d_in[12];
    float* out = (float*)d_out;

    char* ws = (char*)d_ws;
    float* red      = (float*)(ws + 0);     // [129]
    float* pre      = (float*)(ws + 1024);  // [640]
    float* partials = (float*)(ws + 4096);  // [129][G1]

    k_pre<<<160, 256, 0, stream>>>(Wi, bi, Wh, bh, x, h, pre);
    k_dict<<<G1, 256, 0, stream>>>(keys, vals, x, out + KEYS_OFF, out + VALS_OFF, partials);
    k_red<<<129, 256, 0, stream>>>(partials, red);
    k_tail<<<1, 256, 0, stream>>>(red, pre, x, c, Wa, ba, Wc, bc, out);
}

// Round 13
// 183.005 us; speedup vs baseline: 1.0082x; 1.0082x over previous
//
#include <hip/hip_runtime.h>
#include <hip/hip_bf16.h>
#include <math.h>

#define DICT 400000
#define D 128
#define NPAIR (DICT / 2)
#define G1 1536
#define KEYS_OFF 273
#define VALS_OFF (273 + DICT * D)
#define SHIFT 16.0f  // fixed softmax shift; cancels in num/den.

typedef float vfloat4 __attribute__((ext_vector_type(4)));

// ---------------- k_pre: preact = W_i2h@x + b_i2h + W_h2h@h + b_h2h (640 rows)
__global__ __launch_bounds__(256) void k_pre(const float* __restrict__ Wi,
                                             const float* __restrict__ bi,
                                             const float* __restrict__ Wh,
                                             const float* __restrict__ bh,
                                             const float* __restrict__ x,
                                             const float* __restrict__ h,
                                             float* __restrict__ pre) {
    const int lane = threadIdx.x & 63;
    const int row = blockIdx.x * 4 + (threadIdx.x >> 6);
    if (row >= 640) return;
    float2 xv = reinterpret_cast<const float2*>(x)[lane];
    float2 hv = reinterpret_cast<const float2*>(h)[lane];
    float2 wi = reinterpret_cast<const float2*>(Wi + row * D)[lane];
    float2 wh = reinterpret_cast<const float2*>(Wh + row * D)[lane];
    float dot = wi.x * xv.x + wi.y * xv.y + wh.x * hv.x + wh.y * hv.y;
#pragma unroll
    for (int off = 32; off; off >>= 1) dot += __shfl_xor(dot, off);
    if (lane == 0) pre[row] = dot + bi[row] + bh[row];
}

// Aligned-window store for pair p (single stream): dst floats
// [(2p+1)*128+15, +256) = 8 full 128B lines, one 1KB wave burst.
// Lane L gets src floats 2p*128+15+4L..: comp0 from srclane L+3 (.w),
// comps1-3 from srclane L+4 (.x/.y/.z); wrap lanes source the NEXT row's
// head (ek lanes 0..3). kv holds src floats 2p*128+4*lane..+4 per lane.
__device__ __forceinline__ void store_window1(float* __restrict__ dst,
                                              vfloat4 kv, vfloat4 ek,
                                              int lane, int idx3, int idx4,
                                              int p, bool last) {
    vfloat4 ks;
    float s;
    s = (lane < 3) ? ek.w : kv.w;  ks.x = __shfl(s, idx3);
    s = (lane < 4) ? ek.x : kv.x;  ks.y = __shfl(s, idx4);
    s = (lane < 4) ? ek.y : kv.y;  ks.z = __shfl(s, idx4);
    s = (lane < 4) ? ek.z : kv.z;  ks.w = __shfl(s, idx4);
    size_t base = (size_t)(2 * p + 1) * 128 + 15 + 4 * (size_t)lane;
    if (!last) {
        *reinterpret_cast<vfloat4*>(dst + base) = ks;
    } else {
        if (lane < 28) *reinterpret_cast<vfloat4*>(dst + base) = ks;
        else if (lane == 28) dst[base] = ks.x;
    }
}

// ---------------- k_dict: PHASE-SPLIT fused sweep, 24 waves/CU.
// launch_bounds(256, 6) caps VGPR ~84 (body has 3 live float4 streams ->
// should fit, unlike the 64-cap that spilled in round 12). G1=1536 = exactly
// 6 blocks x 256 CUs, no batch tail. Each phase = 1 read + 1 write stream
// per wave (the m13 copy mix). Strided mapping, aligned windows, cached loads.
__global__ __launch_bounds__(256, 6) void k_dict(const float* __restrict__ keys,
                                                 const float* __restrict__ vals,
                                                 const float* __restrict__ x,
                                                 float* __restrict__ keys_new,
                                                 float* __restrict__ vals_new,
                                                 float* __restrict__ partials) {
    const int tid = threadIdx.x;
    const int lane = tid & 63;
    const int half = lane >> 5;   // which row of the pair
    const int hl = lane & 31;     // lane within 32-lane half (4 floats each)
    const int wv = tid >> 6;      // wave in block
    const int idx3 = (lane + 3) & 63;
    const int idx4 = (lane + 4) & 63;
    const int wave = (blockIdx.x * blockDim.x + tid) >> 6;
    const int nw = (gridDim.x * blockDim.x) >> 6;
    const float4 xv = reinterpret_cast<const float4*>(x)[hl];

    // e storage: [wave][4*iter + 2*half + j]; <=17 iters/wave at nw=6144
    __shared__ float e_lds[4][104];

    float den = 0.f;

    // ---------------- PHASE 1: keys ----------------
    {
        int it = 0;
        for (int pp = 2 * wave; pp < NPAIR; pp += 2 * nw, ++it) {
            const int row0 = 2 * pp + half;
            const int row1 = row0 + 2;
            vfloat4 kv0 = reinterpret_cast<const vfloat4*>(keys + (size_t)row0 * D)[hl];
            vfloat4 kv1 = reinterpret_cast<const vfloat4*>(keys + (size_t)row1 * D)[hl];
            vfloat4 ek1 = (vfloat4)(0.f);
            if (lane < 4) {
                const int erow = min(2 * pp + 4, DICT - 1);  // clamp: junk unused
                ek1 = *reinterpret_cast<const vfloat4*>(keys + (size_t)erow * D + 4 * lane);
            }

            float dx = kv0.x - xv.x, dy = kv0.y - xv.y, dz = kv0.z - xv.z, dw = kv0.w - xv.w;
            float d20 = dx * dx + dy * dy + dz * dz + dw * dw;
            dx = kv1.x - xv.x; dy = kv1.y - xv.y; dz = kv1.z - xv.z; dw = kv1.w - xv.w;
            float d21 = dx * dx + dy * dy + dz * dz + dw * dw;
#pragma unroll
            for (int off = 16; off; off >>= 1) {
                d20 += __shfl_xor(d20, off);
                d21 += __shfl_xor(d21, off);
            }
            float e0 = __expf(SHIFT - sqrtf(d20 + 1e-6f));
            float e1 = __expf(SHIFT - sqrtf(d21 + 1e-6f));
            den += e0 + e1;
            if (hl == 0) {
                e_lds[wv][4 * it + 2 * half + 0] = e0;
                e_lds[wv][4 * it + 2 * half + 1] = e1;
            }

            if (pp == 0 && lane < 15) keys_new[128 + lane] = keys[lane];
            store_window1(keys_new, kv0, kv1, lane, idx3, idx4, pp, false);
            store_window1(keys_new, kv1, ek1, lane, idx3, idx4, pp + 1,
                          pp + 1 == NPAIR - 1);
        }
    }

    // ---------------- PHASE 2: vals ----------------
    vfloat4 acc = (vfloat4)(0.f);
    {
        int it = 0;
        for (int pp = 2 * wave; pp < NPAIR; pp += 2 * nw, ++it) {
            const int row0 = 2 * pp + half;
            const int row1 = row0 + 2;
            vfloat4 vv0 = reinterpret_cast<const vfloat4*>(vals + (size_t)row0 * D)[hl];
            vfloat4 vv1 = reinterpret_cast<const vfloat4*>(vals + (size_t)row1 * D)[hl];
            vfloat4 ev1 = (vfloat4)(0.f);
            if (lane < 4) {
                const int erow = min(2 * pp + 4, DICT - 1);
                ev1 = *reinterpret_cast<const vfloat4*>(vals + (size_t)erow * D + 4 * lane);
            }

            float e0 = e_lds[wv][4 * it + 2 * half + 0];
            float e1 = e_lds[wv][4 * it + 2 * half + 1];
            acc.x += e0 * vv0.x + e1 * vv1.x;
            acc.y += e0 * vv0.y + e1 * vv1.y;
            acc.z += e0 * vv0.z + e1 * vv1.z;
            acc.w += e0 * vv0.w + e1 * vv1.w;

            if (pp == 0 && lane < 15) vals_new[128 + lane] = vals[lane];
            store_window1(vals_new, vv0, vv1, lane, idx3, idx4, pp, false);
            store_window1(vals_new, vv1, ev1, lane, idx3, idx4, pp + 1,
                          pp + 1 == NPAIR - 1);
        }
    }

    // merge the two halves (even/odd rows; same component mapping)
    acc.x += __shfl_xor(acc.x, 32);
    acc.y += __shfl_xor(acc.y, 32);
    acc.z += __shfl_xor(acc.z, 32);
    acc.w += __shfl_xor(acc.w, 32);
    den += __shfl_xor(den, 32);

    __shared__ float lnum[4][128];
    __shared__ float lden[4];
    if (lane < 32) {
        lnum[wv][hl * 4 + 0] = acc.x;
        lnum[wv][hl * 4 + 1] = acc.y;
        lnum[wv][hl * 4 + 2] = acc.z;
        lnum[wv][hl * 4 + 3] = acc.w;
    }
    if (lane == 0) lden[wv] = den;
    __syncthreads();
    if (tid < 128) {
        float s = lnum[0][tid] + lnum[1][tid] + lnum[2][tid] + lnum[3][tid];
        partials[(size_t)tid * G1 + blockIdx.x] = s;   // [129][G1] layout
    } else if (tid == 128) {
        partials[(size_t)128 * G1 + blockIdx.x] = lden[0] + lden[1] + lden[2] + lden[3];
    }
}

// ---------------- k_red: reduce partials[129][G1] -> red[129] (coalesced)
__global__ __launch_bounds__(256) void k_red(const float* __restrict__ partials,
                                             float* __restrict__ red) {
    const int j = blockIdx.x;  // 0..128
    float s = 0.f;
    for (int b = threadIdx.x; b < G1; b += 256) s += partials[(size_t)j * G1 + b];
#pragma unroll
    for (int off = 32; off; off >>= 1) s += __shfl_xor(s, off);
    __shared__ float w4[4];
    if ((threadIdx.x & 63) == 0) w4[threadIdx.x >> 6] = s;
    __syncthreads();
    if (threadIdx.x == 0) red[j] = w4[0] + w4[1] + w4[2] + w4[3];
}

// ---------------- k_tail: m_t, LSTM cell, heads, row-0 writes. 1 block.
__global__ __launch_bounds__(256) void k_tail(const float* __restrict__ red,
                                              const float* __restrict__ pre,
                                              const float* __restrict__ x,
                                              const float* __restrict__ c,
                                              const float* __restrict__ Wa,
                                              const float* __restrict__ ba,
                                              const float* __restrict__ Wc,
                                              const float* __restrict__ bc,
                                              float* __restrict__ out) {
    __shared__ float sh_h[128];
    __shared__ float sh_logit[16];
    const int tid = threadIdx.x;
    if (tid < 128) {
        float den = red[128];
        float m = tanhf(red[tid] / den);
        float f  = 1.f / (1.f + __expf(-pre[tid]));
        float i_ = 1.f / (1.f + __expf(-pre[128 + tid]));
        float o  = 1.f / (1.f + __expf(-pre[256 + tid]));
        float r  = 1.f / (1.f + __expf(-pre[384 + tid]));
        float cn = tanhf(pre[512 + tid]);
        float ct = f * c[tid] + i_ * cn + r * m;
        float ht = o * tanhf(ct);
        sh_h[tid] = ht;
        out[17 + tid] = ht;            // h_t
        out[145 + tid] = ct;           // c_t
        out[KEYS_OFF + tid] = x[tid];  // keys_new row 0
        out[VALS_OFF + tid] = ct;      // vals_new row 0
    }
    __syncthreads();
    if (tid < 16) {
        float l = ba[tid];
        for (int j = 0; j < 128; ++j) l += Wa[tid * D + j] * sh_h[j];
        sh_logit[tid] = l;
    } else if (tid == 16) {
        float v = bc[0];
        for (int j = 0; j < 128; ++j) v += Wc[j] * sh_h[j];
        out[16] = v;
    }
    __syncthreads();
    if (tid == 0) {
        float mx = sh_logit[0];
        for (int k = 1; k < 16; ++k) mx = fmaxf(mx, sh_logit[k]);
        float e[16];
        float s = 0.f;
        for (int k = 0; k < 16; ++k) { e[k] = __expf(sh_logit[k] - mx); s += e[k]; }
        for (int k = 0; k < 16; ++k) out[k] = e[k] / s;
    }
}

extern "C" void kernel_launch(void* const* d_in, const int* in_sizes, int n_in,
                              void* d_out, int out_size, void* d_ws, size_t ws_size,
                              hipStream_t stream) {
    const float* x    = (const float*)d_in[0];
    const float* h    = (const float*)d_in[1];
    const float* c    = (const float*)d_in[2];
    const float* Wi   = (const float*)d_in[3];
    const float* bi   = (const float*)d_in[4];
    const float* Wh   = (const float*)d_in[5];
    const float* bh   = (const float*)d_in[6];
    const float* keys = (const float*)d_in[7];
    const float* vals = (const float*)d_in[8];
    const float* Wa   = (const float*)d_in[9];
    const float* ba   = (const float*)d_in[10];
    const float* Wc   = (const float*)d_in[11];
    const float* bc   = (const float*)d_in[12];
    float* out = (float*)d_out;

    char* ws = (char*)d_ws;
    float* red      = (float*)(ws + 0);     // [129]
    float* pre      = (float*)(ws + 1024);  // [640]
    float* partials = (float*)(ws + 4096);  // [129][G1]

    k_pre<<<160, 256, 0, stream>>>(Wi, bi, Wh, bh, x, h, pre);
    k_dict<<<G1, 256, 0, stream>>>(keys, vals, x, out + KEYS_OFF, out + VALS_OFF, partials);
    k_red<<<129, 256, 0, stream>>>(partials, red);
    k_tail<<<1, 256, 0, stream>>>(red, pre, x, c, Wa, ba, Wc, bc, out);
}

// Round 14
// 173.174 us; speedup vs baseline: 1.0654x; 1.0568x over previous
//
#include <hip/hip_runtime.h>
#include <hip/hip_bf16.h>
#include <math.h>

#define DICT 400000
#define D 128
#define NPAIR (DICT / 2)
#define G1 1024
#define KEYS_OFF 273
#define VALS_OFF (273 + DICT * D)
#define SHIFT 16.0f  // fixed softmax shift; cancels in num/den.

typedef float vfloat4 __attribute__((ext_vector_type(4)));

// ---------------- k_pre: preact = W_i2h@x + b_i2h + W_h2h@h + b_h2h (640 rows)
__global__ __launch_bounds__(256) void k_pre(const float* __restrict__ Wi,
                                             const float* __restrict__ bi,
                                             const float* __restrict__ Wh,
                                             const float* __restrict__ bh,
                                             const float* __restrict__ x,
                                             const float* __restrict__ h,
                                             float* __restrict__ pre) {
    const int lane = threadIdx.x & 63;
    const int row = blockIdx.x * 4 + (threadIdx.x >> 6);
    if (row >= 640) return;
    float2 xv = reinterpret_cast<const float2*>(x)[lane];
    float2 hv = reinterpret_cast<const float2*>(h)[lane];
    float2 wi = reinterpret_cast<const float2*>(Wi + row * D)[lane];
    float2 wh = reinterpret_cast<const float2*>(Wh + row * D)[lane];
    float dot = wi.x * xv.x + wi.y * xv.y + wh.x * hv.x + wh.y * hv.y;
#pragma unroll
    for (int off = 32; off; off >>= 1) dot += __shfl_xor(dot, off);
    if (lane == 0) pre[row] = dot + bi[row] + bh[row];
}

// Aligned-window store for pair p (single stream): dst floats
// [(2p+1)*128+15, +256) = 8 full 128B lines, one 1KB wave burst.
// Lane L gets src floats 2p*128+15+4L..: comp0 from srclane L+3 (.w),
// comps1-3 from srclane L+4 (.x/.y/.z); wrap lanes source the NEXT row's
// head (ek lanes 0..3). kv holds src floats 2p*128+4*lane..+4 per lane.
__device__ __forceinline__ void store_window1(float* __restrict__ dst,
                                              vfloat4 kv, vfloat4 ek,
                                              int lane, int idx3, int idx4,
                                              int p, bool last) {
    vfloat4 ks;
    float s;
    s = (lane < 3) ? ek.w : kv.w;  ks.x = __shfl(s, idx3);
    s = (lane < 4) ? ek.x : kv.x;  ks.y = __shfl(s, idx4);
    s = (lane < 4) ? ek.y : kv.y;  ks.z = __shfl(s, idx4);
    s = (lane < 4) ? ek.z : kv.z;  ks.w = __shfl(s, idx4);
    size_t base = (size_t)(2 * p + 1) * 128 + 15 + 4 * (size_t)lane;
    if (!last) {
        *reinterpret_cast<vfloat4*>(dst + base) = ks;
    } else {
        if (lane < 28) *reinterpret_cast<vfloat4*>(dst + base) = ks;
        else if (lane == 28) dst[base] = ks.x;
    }
}

// ---------------- k_dict: PHASE-SPLIT fused sweep (round-11 best config).
// Phase 1: keys stream only  (read keys -> e per row -> LDS; copy keys_new).
// Phase 2: vals stream only  (read vals -> acc += e*v from LDS; copy vals_new).
// Each phase = 1 read + 1 write stream per wave (the m13 copy mix).
// Strided mapping, aligned windows, cached loads, G1=1024, no VGPR cap
// (4 blocks/CU; any higher occupancy cap spills and regresses — r12/r13).
__global__ __launch_bounds__(256) void k_dict(const float* __restrict__ keys,
                                              const float* __restrict__ vals,
                                              const float* __restrict__ x,
                                              float* __restrict__ keys_new,
                                              float* __restrict__ vals_new,
                                              float* __restrict__ partials) {
    const int tid = threadIdx.x;
    const int lane = tid & 63;
    const int half = lane >> 5;   // which row of the pair
    const int hl = lane & 31;     // lane within 32-lane half (4 floats each)
    const int wv = tid >> 6;      // wave in block
    const int idx3 = (lane + 3) & 63;
    const int idx4 = (lane + 4) & 63;
    const int wave = (blockIdx.x * blockDim.x + tid) >> 6;
    const int nw = (gridDim.x * blockDim.x) >> 6;
    const float4 xv = reinterpret_cast<const float4*>(x)[hl];

    // e storage: [wave][4*iter + 2*half + j]; <=25 iters/wave at nw=4096
    __shared__ float e_lds[4][104];

    float den = 0.f;

    // ---------------- PHASE 1: keys ----------------
    {
        int it = 0;
        for (int pp = 2 * wave; pp < NPAIR; pp += 2 * nw, ++it) {
            const int row0 = 2 * pp + half;
            const int row1 = row0 + 2;
            vfloat4 kv0 = reinterpret_cast<const vfloat4*>(keys + (size_t)row0 * D)[hl];
            vfloat4 kv1 = reinterpret_cast<const vfloat4*>(keys + (size_t)row1 * D)[hl];
            vfloat4 ek1 = (vfloat4)(0.f);
            if (lane < 4) {
                const int erow = min(2 * pp + 4, DICT - 1);  // clamp: junk unused
                ek1 = *reinterpret_cast<const vfloat4*>(keys + (size_t)erow * D + 4 * lane);
            }

            float dx = kv0.x - xv.x, dy = kv0.y - xv.y, dz = kv0.z - xv.z, dw = kv0.w - xv.w;
            float d20 = dx * dx + dy * dy + dz * dz + dw * dw;
            dx = kv1.x - xv.x; dy = kv1.y - xv.y; dz = kv1.z - xv.z; dw = kv1.w - xv.w;
            float d21 = dx * dx + dy * dy + dz * dz + dw * dw;
#pragma unroll
            for (int off = 16; off; off >>= 1) {
                d20 += __shfl_xor(d20, off);
                d21 += __shfl_xor(d21, off);
            }
            float e0 = __expf(SHIFT - sqrtf(d20 + 1e-6f));
            float e1 = __expf(SHIFT - sqrtf(d21 + 1e-6f));
            den += e0 + e1;
            if (hl == 0) {
                e_lds[wv][4 * it + 2 * half + 0] = e0;
                e_lds[wv][4 * it + 2 * half + 1] = e1;
            }

            if (pp == 0 && lane < 15) keys_new[128 + lane] = keys[lane];
            store_window1(keys_new, kv0, kv1, lane, idx3, idx4, pp, false);
            store_window1(keys_new, kv1, ek1, lane, idx3, idx4, pp + 1,
                          pp + 1 == NPAIR - 1);
        }
    }

    // ---------------- PHASE 2: vals ----------------
    vfloat4 acc = (vfloat4)(0.f);
    {
        int it = 0;
        for (int pp = 2 * wave; pp < NPAIR; pp += 2 * nw, ++it) {
            const int row0 = 2 * pp + half;
            const int row1 = row0 + 2;
            vfloat4 vv0 = reinterpret_cast<const vfloat4*>(vals + (size_t)row0 * D)[hl];
            vfloat4 vv1 = reinterpret_cast<const vfloat4*>(vals + (size_t)row1 * D)[hl];
            vfloat4 ev1 = (vfloat4)(0.f);
            if (lane < 4) {
                const int erow = min(2 * pp + 4, DICT - 1);
                ev1 = *reinterpret_cast<const vfloat4*>(vals + (size_t)erow * D + 4 * lane);
            }

            float e0 = e_lds[wv][4 * it + 2 * half + 0];
            float e1 = e_lds[wv][4 * it + 2 * half + 1];
            acc.x += e0 * vv0.x + e1 * vv1.x;
            acc.y += e0 * vv0.y + e1 * vv1.y;
            acc.z += e0 * vv0.z + e1 * vv1.z;
            acc.w += e0 * vv0.w + e1 * vv1.w;

            if (pp == 0 && lane < 15) vals_new[128 + lane] = vals[lane];
            store_window1(vals_new, vv0, vv1, lane, idx3, idx4, pp, false);
            store_window1(vals_new, vv1, ev1, lane, idx3, idx4, pp + 1,
                          pp + 1 == NPAIR - 1);
        }
    }

    // merge the two halves (even/odd rows; same component mapping)
    acc.x += __shfl_xor(acc.x, 32);
    acc.y += __shfl_xor(acc.y, 32);
    acc.z += __shfl_xor(acc.z, 32);
    acc.w += __shfl_xor(acc.w, 32);
    den += __shfl_xor(den, 32);

    __shared__ float lnum[4][128];
    __shared__ float lden[4];
    if (lane < 32) {
        lnum[wv][hl * 4 + 0] = acc.x;
        lnum[wv][hl * 4 + 1] = acc.y;
        lnum[wv][hl * 4 + 2] = acc.z;
        lnum[wv][hl * 4 + 3] = acc.w;
    }
    if (lane == 0) lden[wv] = den;
    __syncthreads();
    if (tid < 128) {
        float s = lnum[0][tid] + lnum[1][tid] + lnum[2][tid] + lnum[3][tid];
        partials[(size_t)tid * G1 + blockIdx.x] = s;   // [129][G1] layout
    } else if (tid == 128) {
        partials[(size_t)128 * G1 + blockIdx.x] = lden[0] + lden[1] + lden[2] + lden[3];
    }
}

// ---------------- k_red: reduce partials[129][G1] -> red[129] (coalesced)
__global__ __launch_bounds__(256) void k_red(const float* __restrict__ partials,
                                             float* __restrict__ red) {
    const int j = blockIdx.x;  // 0..128
    float s = 0.f;
    for (int b = threadIdx.x; b < G1; b += 256) s += partials[(size_t)j * G1 + b];
#pragma unroll
    for (int off = 32; off; off >>= 1) s += __shfl_xor(s, off);
    __shared__ float w4[4];
    if ((threadIdx.x & 63) == 0) w4[threadIdx.x >> 6] = s;
    __syncthreads();
    if (threadIdx.x == 0) red[j] = w4[0] + w4[1] + w4[2] + w4[3];
}

// ---------------- k_tail: m_t, LSTM cell, heads, row-0 writes. 1 block.
__global__ __launch_bounds__(256) void k_tail(const float* __restrict__ red,
                                              const float* __restrict__ pre,
                                              const float* __restrict__ x,
                                              const float* __restrict__ c,
                                              const float* __restrict__ Wa,
                                              const float* __restrict__ ba,
                                              const float* __restrict__ Wc,
                                              const float* __restrict__ bc,
                                              float* __restrict__ out) {
    __shared__ float sh_h[128];
    __shared__ float sh_logit[16];
    const int tid = threadIdx.x;
    if (tid < 128) {
        float den = red[128];
        float m = tanhf(red[tid] / den);
        float f  = 1.f / (1.f + __expf(-pre[tid]));
        float i_ = 1.f / (1.f + __expf(-pre[128 + tid]));
        float o  = 1.f / (1.f + __expf(-pre[256 + tid]));
        float r  = 1.f / (1.f + __expf(-pre[384 + tid]));
        float cn = tanhf(pre[512 + tid]);
        float ct = f * c[tid] + i_ * cn + r * m;
        float ht = o * tanhf(ct);
        sh_h[tid] = ht;
        out[17 + tid] = ht;            // h_t
        out[145 + tid] = ct;           // c_t
        out[KEYS_OFF + tid] = x[tid];  // keys_new row 0
        out[VALS_OFF + tid] = ct;      // vals_new row 0
    }
    __syncthreads();
    if (tid < 16) {
        float l = ba[tid];
        for (int j = 0; j < 128; ++j) l += Wa[tid * D + j] * sh_h[j];
        sh_logit[tid] = l;
    } else if (tid == 16) {
        float v = bc[0];
        for (int j = 0; j < 128; ++j) v += Wc[j] * sh_h[j];
        out[16] = v;
    }
    __syncthreads();
    if (tid == 0) {
        float mx = sh_logit[0];
        for (int k = 1; k < 16; ++k) mx = fmaxf(mx, sh_logit[k]);
        float e[16];
        float s = 0.f;
        for (int k = 0; k < 16; ++k) { e[k] = __expf(sh_logit[k] - mx); s += e[k]; }
        for (int k = 0; k < 16; ++k) out[k] = e[k] / s;
    }
}

extern "C" void kernel_launch(void* const* d_in, const int* in_sizes, int n_in,
                              void* d_out, int out_size, void* d_ws, size_t ws_size,
                              hipStream_t stream) {
    const float* x    = (const float*)d_in[0];
    const float* h    = (const float*)d_in[1];
    const float* c    = (const float*)d_in[2];
    const float* Wi   = (const float*)d_in[3];
    const float* bi   = (const float*)d_in[4];
    const float* Wh   = (const float*)d_in[5];
    const float* bh   = (const float*)d_in[6];
    const float* keys = (const float*)d_in[7];
    const float* vals = (const float*)d_in[8];
    const float* Wa   = (const float*)d_in[9];
    const float* ba   = (const float*)d_in[10];
    const float* Wc   = (const float*)d_in[11];
    const float* bc   = (const float*)d_in[12];
    float* out = (float*)d_out;

    char* ws = (char*)d_ws;
    float* red      = (float*)(ws + 0);     // [129]
    float* pre      = (float*)(ws + 1024);  // [640]
    float* partials = (float*)(ws + 4096);  // [129][G1]

    k_pre<<<160, 256, 0, stream>>>(Wi, bi, Wh, bh, x, h, pre);
    k_dict<<<G1, 256, 0, stream>>>(keys, vals, x, out + KEYS_OFF, out + VALS_OFF, partials);
    k_red<<<129, 256, 0, stream>>>(partials, red);
    k_tail<<<1, 256, 0, stream>>>(red, pre, x, c, Wa, ba, Wc, bc, out);
}